// Round 3
// baseline (3547.480 us; speedup 1.0000x reference)
//
#include <hip/hip_runtime.h>
#include <hip/hip_bf16.h>

#define NN 10000
#define NE 100000

typedef __bf16 bf16x8 __attribute__((ext_vector_type(8)));
typedef __bf16 bf16x4 __attribute__((ext_vector_type(4)));
typedef float  f32x4  __attribute__((ext_vector_type(4)));

__device__ __forceinline__ f32x4 relu4(f32x4 a) {
    a.x = fmaxf(a.x, 0.f); a.y = fmaxf(a.y, 0.f);
    a.z = fmaxf(a.z, 0.f); a.w = fmaxf(a.w, 0.f);
    return a;
}

// ---------------- one-time kernels ----------------

__global__ void k_deg(const int* __restrict__ eidx, int* __restrict__ deg) {
    int e = blockIdx.x * blockDim.x + threadIdx.x;
    if (e < NE) atomicAdd(&deg[eidx[e]], 1);
}

__global__ void k_init(const float* __restrict__ x, const float* __restrict__ fc1w,
                       const float* __restrict__ fc1b, const float* __restrict__ cinit,
                       const int* __restrict__ deg,
                       float* __restrict__ h, float* __restrict__ coord,
                       float* __restrict__ deg_inv) {
    int n = blockIdx.x * blockDim.x + threadIdx.x;
    if (n >= NN) return;
    float x0 = x[n*3+0], x1 = x[n*3+1], x2 = x[n*3+2];
    #pragma unroll
    for (int j = 0; j < 32; j += 4) {
        f32x4 a = *(const f32x4*)(fc1b + j);
        a += x0 * (*(const f32x4*)(fc1w + 0*32 + j));
        a += x1 * (*(const f32x4*)(fc1w + 1*32 + j));
        a += x2 * (*(const f32x4*)(fc1w + 2*32 + j));
        *(f32x4*)(h + n*32 + j) = a;   // no relu on fc1 (matches reference)
    }
    coord[n*3+0] = cinit[n*3+0];
    coord[n*3+1] = cinit[n*3+1];
    coord[n*3+2] = cinit[n*3+2];
    int d = deg[n];
    deg_inv[n] = 1.0f / (float)(d > 1 ? d : 1);
}

// Swizzle ker_w3 [128,1024] fp32 -> bf16 in MFMA-B fragment order.
__global__ void k_w3sw(const float* __restrict__ w3, __bf16* __restrict__ w3sw) {
    int t = blockIdx.x * blockDim.x + threadIdx.x;   // 0 .. 131071
    int jj = t & 7;
    int L  = (t >> 3) & 63;
    int ks = (t >> 9) & 3;
    int jt = (t >> 11) & 1;
    int i  = t >> 12;
    int c    = ks*32 + (L >> 4)*8 + jj;              // K index 0..127
    int colv = i*32 + jt*16 + (L & 15);              // output col 0..1023
    w3sw[t] = (__bf16)w3[c*1024 + colv];
}

// ---------------- per-layer kernels ----------------

// Per-edge: coord_diff, radial, kernel MLP 7->64->128 (relu), store k as bf16 [E,128].
// RESTRUCTURED: no 64-element live array. Outputs tiled 4x32 (8 f32x4 acc);
// k1 recomputed per tile in chunks of 8. Max live ~55 regs -> fits the 64-VGPR
// cap the allocator insists on (round1/2: k1[64] spilled -> 866 MB scratch reads).
__global__ __launch_bounds__(256, 2)
void k_edge(const float* __restrict__ coord, const int* __restrict__ eidx,
            const float* __restrict__ eattr,
            const float* __restrict__ w1, const float* __restrict__ b1,
            const float* __restrict__ w2, const float* __restrict__ b2,
            float* __restrict__ cd4, __bf16* __restrict__ kbf) {
    int e = blockIdx.x * blockDim.x + threadIdx.x;
    if (e >= NE) return;
    int r = eidx[e], c = eidx[NE + e];
    float dx = coord[r*3+0] - coord[c*3+0];
    float dy = coord[r*3+1] - coord[c*3+1];
    float dz = coord[r*3+2] - coord[c*3+2];
    float rad = dx*dx + dy*dy + dz*dz;
    f32x4 cdv = {dx, dy, dz, rad};
    *(f32x4*)(cd4 + (size_t)e*4) = cdv;

    float kin[7];
    #pragma unroll
    for (int a = 0; a < 6; ++a) kin[a] = eattr[(size_t)e*6 + a];
    kin[6] = rad;

    for (int c2t = 0; c2t < 4; ++c2t) {            // output tile: 32 channels
        const int c2 = c2t * 32;
        f32x4 acc[8];
        #pragma unroll
        for (int g = 0; g < 8; ++g) acc[g] = *(const f32x4*)(b2 + c2 + g*4);

        #pragma unroll
        for (int c1c = 0; c1c < 8; ++c1c) {        // k1 chunk of 8
            float k1c[8];
            #pragma unroll
            for (int jj = 0; jj < 8; jj += 4) {
                int j = c1c*8 + jj;
                f32x4 a = *(const f32x4*)(b1 + j);
                #pragma unroll
                for (int t = 0; t < 7; ++t)
                    a += kin[t] * (*(const f32x4*)(w1 + t*64 + j));
                a = relu4(a);
                k1c[jj+0] = a.x; k1c[jj+1] = a.y; k1c[jj+2] = a.z; k1c[jj+3] = a.w;
            }
            #pragma unroll
            for (int l = 0; l < 8; ++l) {
                const float kv = k1c[l];
                const float* wr = w2 + (c1c*8 + l)*128 + c2;
                #pragma unroll
                for (int g = 0; g < 8; ++g)
                    acc[g] += kv * (*(const f32x4*)(wr + g*4));
            }
        }
        #pragma unroll
        for (int g = 0; g < 8; ++g) {
            f32x4 a = relu4(acc[g]);
            bf16x4 pk = {(__bf16)a.x, (__bf16)a.y, (__bf16)a.z, (__bf16)a.w};
            *(bf16x4*)(kbf + (size_t)e*128 + c2 + g*4) = pk;
        }
    }
}

// Fused: big GEMM (E x 128 x 1024) with einsum epilogue -> m[e][i] in regs,
// then phi MLP + atomic scatter. One wave / 64 edges per block.
__global__ __launch_bounds__(64, 1)
void k_gemm(const __bf16* __restrict__ kbf, const __bf16* __restrict__ w3sw,
            const float* __restrict__ b3, const float* __restrict__ h,
            const int* __restrict__ eidx, const float* __restrict__ cd4,
            const float* __restrict__ cm_w1, const float* __restrict__ cm_b1,
            const float* __restrict__ cm_w2,
            float* __restrict__ acc_coord, float* __restrict__ acc_m) {
    __shared__ float wk[64 * 34];          // row pad 34 -> <=2-way bank conflicts
    const int lane = threadIdx.x;          // 0..63
    const int q = lane >> 4, t = lane & 15;
    const int base = blockIdx.x * 64;

    // gather h[col] for this lane's edge into registers
    int eg = base + lane;
    int egc = eg < NE ? eg : NE - 1;
    int col = eidx[NE + egc];
    float hcol[32];
    const f32x4* hp = (const f32x4*)(h + (size_t)col * 32);
    #pragma unroll
    for (int v = 0; v < 8; ++v) {
        f32x4 hv = hp[v];
        hcol[v*4+0] = hv.x; hcol[v*4+1] = hv.y; hcol[v*4+2] = hv.z; hcol[v*4+3] = hv.w;
    }

    // A fragments: lane supplies A[m=t][k=q*8..q*8+7] for 4 M-tiles x 4 K-steps
    bf16x8 afrag[4][4];
    #pragma unroll
    for (int mt = 0; mt < 4; ++mt) {
        int ea = base + mt*16 + t;
        ea = ea < NE ? ea : NE - 1;
        const __bf16* kr = kbf + (size_t)ea * 128 + q * 8;
        #pragma unroll
        for (int ks = 0; ks < 4; ++ks)
            afrag[mt][ks] = *(const bf16x8*)(kr + ks * 32);
    }

    const bool wvalid = eg < NE;
    const float* wkrow = wk + lane * 34;
    float mv[32];

    for (int i = 0; i < 32; ++i) {
        f32x4 acc[4][2];
        #pragma unroll
        for (int mt = 0; mt < 4; ++mt) {
            acc[mt][0] = (f32x4){0.f, 0.f, 0.f, 0.f};
            acc[mt][1] = (f32x4){0.f, 0.f, 0.f, 0.f};
        }
        const __bf16* wb = w3sw + (size_t)i * 4096;
        #pragma unroll
        for (int jt = 0; jt < 2; ++jt) {
            #pragma unroll
            for (int ks = 0; ks < 4; ++ks) {
                bf16x8 bfrag = *(const bf16x8*)(wb + ((jt*4 + ks)*64 + lane) * 8);
                #pragma unroll
                for (int mt = 0; mt < 4; ++mt)
                    acc[mt][jt] = __builtin_amdgcn_mfma_f32_16x16x32_bf16(
                        afrag[mt][ks], bfrag, acc[mt][jt], 0, 0, 0);
            }
        }
        float bias0 = b3[i*32 + t];
        float bias1 = b3[i*32 + 16 + t];
        __syncthreads();   // prev iteration's reads done
        #pragma unroll
        for (int mt = 0; mt < 4; ++mt) {
            #pragma unroll
            for (int r = 0; r < 4; ++r) {
                int row = mt*16 + q*4 + r;
                wk[row*34 + t]      = acc[mt][0][r] + bias0;
                wk[row*34 + 16 + t] = acc[mt][1][r] + bias1;
            }
        }
        __syncthreads();
        float s = 0.f;
        #pragma unroll
        for (int j = 0; j < 32; ++j) s += wkrow[j] * hcol[j];
        mv[i] = s;
    }

    // ---- fused phi MLP (32 -> 32 relu -> 1) ----
    float phi = 0.f;
    for (int o = 0; o < 32; o += 4) {
        f32x4 a = *(const f32x4*)(cm_b1 + o);
        #pragma unroll
        for (int i = 0; i < 32; ++i)
            a += mv[i] * (*(const f32x4*)(cm_w1 + i*32 + o));
        a = relu4(a);
        f32x4 w2 = *(const f32x4*)(cm_w2 + o);
        phi += a.x*w2.x + a.y*w2.y + a.z*w2.z + a.w*w2.w;
    }

    if (wvalid) {
        int r = eidx[eg];
        f32x4 cd = *(const f32x4*)(cd4 + (size_t)eg*4);
        atomicAdd(&acc_coord[r*3+0], cd.x * phi);
        atomicAdd(&acc_coord[r*3+1], cd.y * phi);
        atomicAdd(&acc_coord[r*3+2], cd.z * phi);
        float* am = acc_m + (size_t)r * 32;
        #pragma unroll
        for (int i = 0; i < 32; ++i) atomicAdd(&am[i], mv[i]);
    }
}

__global__ void k_node(const float* __restrict__ acc_coord, const float* __restrict__ acc_m,
                       const float* __restrict__ deg_inv,
                       float* __restrict__ coord, float* __restrict__ h) {
    int n = blockIdx.x * blockDim.x + threadIdx.x;
    if (n >= NN) return;
    float di = deg_inv[n];
    coord[n*3+0] += acc_coord[n*3+0] * di;
    coord[n*3+1] += acc_coord[n*3+1] * di;
    coord[n*3+2] += acc_coord[n*3+2] * di;
    #pragma unroll
    for (int j = 0; j < 32; j += 4) {
        f32x4 hv = *(const f32x4*)(h + n*32 + j);
        f32x4 av = *(const f32x4*)(acc_m + n*32 + j);
        hv = relu4(hv + av * di);
        *(f32x4*)(h + n*32 + j) = hv;
    }
}

__global__ __launch_bounds__(256, 4)
void k_final(const float* __restrict__ h, const float* __restrict__ coord,
             const float* __restrict__ fw1, const float* __restrict__ fb1,
             const float* __restrict__ fw2, const float* __restrict__ fb2,
             float* __restrict__ out) {
    int n = blockIdx.x * blockDim.x + threadIdx.x;
    if (n >= NN) return;
    float hreg[32];
    #pragma unroll
    for (int i = 0; i < 32; ++i) hreg[i] = h[n*32 + i];
    float ov = fb2[0];
    for (int o = 0; o < 64; o += 4) {
        f32x4 a = *(const f32x4*)(fb1 + o);
        #pragma unroll
        for (int i = 0; i < 32; ++i)
            a += hreg[i] * (*(const f32x4*)(fw1 + i*64 + o));
        a = relu4(a);
        f32x4 w2 = *(const f32x4*)(fw2 + o);
        ov += a.x*w2.x + a.y*w2.y + a.z*w2.z + a.w*w2.w;
    }
    out[n] = ov;                       // output 0: [N,1]
    out[NN + n*3 + 0] = coord[n*3+0];  // output 1: coord [N,3]
    out[NN + n*3 + 1] = coord[n*3+1];
    out[NN + n*3 + 2] = coord[n*3+2];
}

// ---------------- launch ----------------

extern "C" void kernel_launch(void* const* d_in, const int* in_sizes, int n_in,
                              void* d_out, int out_size, void* d_ws, size_t ws_size,
                              hipStream_t stream) {
    const float* x      = (const float*)d_in[0];
    const int*   eidx   = (const int*)  d_in[1];
    const float* eattr  = (const float*)d_in[2];
    const float* cinit  = (const float*)d_in[3];
    const float* fc1w   = (const float*)d_in[4];
    const float* fc1b   = (const float*)d_in[5];
    const float* kw1    = (const float*)d_in[6];
    const float* kb1    = (const float*)d_in[7];
    const float* kw2    = (const float*)d_in[8];
    const float* kb2    = (const float*)d_in[9];
    const float* kw3    = (const float*)d_in[10];
    const float* kb3    = (const float*)d_in[11];
    const float* cmw1   = (const float*)d_in[12];
    const float* cmb1   = (const float*)d_in[13];
    const float* cmw2   = (const float*)d_in[14];
    const float* f2w1   = (const float*)d_in[15];
    const float* f2b1   = (const float*)d_in[16];
    const float* f2w2   = (const float*)d_in[17];
    const float* f2b2   = (const float*)d_in[18];
    float* out = (float*)d_out;

    // workspace carve-up (256B aligned slots)
    char* p = (char*)d_ws;
    auto carve = [&](size_t bytes) {
        void* r = (void*)p;
        p += (bytes + 255) & ~(size_t)255;
        return r;
    };
    float*  h        = (float*) carve((size_t)NN * 32 * 4);
    float*  coord    = (float*) carve((size_t)NN * 3 * 4);
    int*    deg      = (int*)   carve((size_t)NN * 4);
    float*  deg_inv  = (float*) carve((size_t)NN * 4);
    float*  acc      = (float*) carve((size_t)NN * 35 * 4);  // [N*3 coord | N*32 m]
    float*  cd4      = (float*) carve((size_t)NE * 4 * 4);
    __bf16* kbf      = (__bf16*)carve((size_t)NE * 128 * 2);
    __bf16* w3sw     = (__bf16*)carve((size_t)131072 * 2);
    float*  acc_c    = acc;
    float*  acc_m    = acc + (size_t)NN * 3;

    const int TB = 256;
    dim3 gE((NE + TB - 1) / TB), gN((NN + TB - 1) / TB), b(TB);

    hipMemsetAsync(deg, 0, (size_t)NN * 4, stream);
    k_deg <<<gE, b, 0, stream>>>(eidx, deg);
    k_init<<<gN, b, 0, stream>>>(x, fc1w, fc1b, cinit, deg, h, coord, deg_inv);
    k_w3sw<<<512, b, 0, stream>>>(kw3, w3sw);

    for (int d = 0; d < 3; ++d) {
        hipMemsetAsync(acc, 0, (size_t)NN * 35 * 4, stream);
        k_edge<<<gE, b, 0, stream>>>(coord, eidx, eattr, kw1, kb1, kw2, kb2, cd4, kbf);
        k_gemm<<<dim3((NE + 63) / 64), dim3(64), 0, stream>>>(
            kbf, w3sw, kb3, h, eidx, cd4, cmw1, cmb1, cmw2, acc_c, acc_m);
        k_node<<<gN, b, 0, stream>>>(acc_c, acc_m, deg_inv, coord, h);
    }
    k_final<<<gN, b, 0, stream>>>(h, coord, f2w1, f2b1, f2w2, f2b2, out);
}

// Round 4
// 1722.812 us; speedup vs baseline: 2.0591x; 2.0591x over previous
//
#include <hip/hip_runtime.h>
#include <hip/hip_bf16.h>

#define NN 10000
#define NE 100000

typedef __bf16 bf16x8 __attribute__((ext_vector_type(8)));
typedef __bf16 bf16x4 __attribute__((ext_vector_type(4)));
typedef float  f32x4  __attribute__((ext_vector_type(4)));

__device__ __forceinline__ f32x4 relu4(f32x4 a) {
    a.x = fmaxf(a.x, 0.f); a.y = fmaxf(a.y, 0.f);
    a.z = fmaxf(a.z, 0.f); a.w = fmaxf(a.w, 0.f);
    return a;
}

// ---------------- one-time kernels ----------------

__global__ void k_deg(const int* __restrict__ eidx, int* __restrict__ deg) {
    int e = blockIdx.x * blockDim.x + threadIdx.x;
    if (e < NE) atomicAdd(&deg[eidx[e]], 1);
}

__global__ void k_init(const float* __restrict__ x, const float* __restrict__ fc1w,
                       const float* __restrict__ fc1b, const float* __restrict__ cinit,
                       const int* __restrict__ deg,
                       float* __restrict__ h, float* __restrict__ coord,
                       float* __restrict__ deg_inv) {
    int n = blockIdx.x * blockDim.x + threadIdx.x;
    if (n >= NN) return;
    float x0 = x[n*3+0], x1 = x[n*3+1], x2 = x[n*3+2];
    #pragma unroll
    for (int j = 0; j < 32; j += 4) {
        f32x4 a = *(const f32x4*)(fc1b + j);
        a += x0 * (*(const f32x4*)(fc1w + 0*32 + j));
        a += x1 * (*(const f32x4*)(fc1w + 1*32 + j));
        a += x2 * (*(const f32x4*)(fc1w + 2*32 + j));
        *(f32x4*)(h + n*32 + j) = a;   // no relu on fc1 (matches reference)
    }
    coord[n*3+0] = cinit[n*3+0];
    coord[n*3+1] = cinit[n*3+1];
    coord[n*3+2] = cinit[n*3+2];
    int d = deg[n];
    deg_inv[n] = 1.0f / (float)(d > 1 ? d : 1);
}

// Swizzle ker_w3 [128,1024] fp32 -> bf16 in MFMA-B fragment order.
__global__ void k_w3sw(const float* __restrict__ w3, __bf16* __restrict__ w3sw) {
    int t = blockIdx.x * blockDim.x + threadIdx.x;   // 0 .. 131071
    int jj = t & 7;
    int L  = (t >> 3) & 63;
    int ks = (t >> 9) & 3;
    int jt = (t >> 11) & 1;
    int i  = t >> 12;
    int c    = ks*32 + (L >> 4)*8 + jj;              // K index 0..127
    int colv = i*32 + jt*16 + (L & 15);              // output col 0..1023
    w3sw[t] = (__bf16)w3[c*1024 + colv];
}

// Swizzle ker_w2 [64,128] fp32 -> bf16 in MFMA-B fragment order (K=64 -> 2 k-steps).
__global__ void k_w2sw(const float* __restrict__ w2, __bf16* __restrict__ w2sw) {
    int t = blockIdx.x * blockDim.x + threadIdx.x;   // 0 .. 8191
    if (t >= 8192) return;
    int jj = t & 7;
    int L  = (t >> 3) & 63;
    int ks = (t >> 9) & 1;
    int nt = t >> 10;                                // 0..7
    int c1 = ks*32 + (L >> 4)*8 + jj;                // K index 0..63
    int c2 = nt*16 + (L & 15);                       // output col 0..127
    w2sw[t] = (__bf16)w2[c1*128 + c2];
}

// ---------------- per-layer kernels ----------------

// Layer 1 of kernel MLP: 2 threads per edge, each computes 32 of 64 channels.
// Max ~50 live VGPRs by construction -> no spill possible at the 64-reg cap.
__global__ void k_edge1(const float* __restrict__ coord, const int* __restrict__ eidx,
                        const float* __restrict__ eattr,
                        const float* __restrict__ w1, const float* __restrict__ b1,
                        float* __restrict__ cd4, __bf16* __restrict__ k1) {
    int tid = blockIdx.x * blockDim.x + threadIdx.x;
    int e = tid >> 1, hf = tid & 1;
    if (e >= NE) return;
    int r = eidx[e], c = eidx[NE + e];
    float dx = coord[r*3+0] - coord[c*3+0];
    float dy = coord[r*3+1] - coord[c*3+1];
    float dz = coord[r*3+2] - coord[c*3+2];
    float rad = dx*dx + dy*dy + dz*dz;
    if (hf == 0) {
        f32x4 cdv = {dx, dy, dz, rad};
        *(f32x4*)(cd4 + (size_t)e*4) = cdv;
    }
    float kin[7];
    #pragma unroll
    for (int a = 0; a < 6; ++a) kin[a] = eattr[(size_t)e*6 + a];
    kin[6] = rad;

    const int off = hf * 32;
    f32x4 acc[8];
    #pragma unroll
    for (int g = 0; g < 8; ++g) acc[g] = *(const f32x4*)(b1 + off + g*4);
    #pragma unroll
    for (int t = 0; t < 7; ++t) {
        float kv = kin[t];
        #pragma unroll
        for (int g = 0; g < 8; ++g)
            acc[g] += kv * (*(const f32x4*)(w1 + t*64 + off + g*4));
    }
    #pragma unroll
    for (int v = 0; v < 4; ++v) {
        f32x4 a0 = relu4(acc[2*v]), a1 = relu4(acc[2*v+1]);
        bf16x8 pk = {(__bf16)a0.x, (__bf16)a0.y, (__bf16)a0.z, (__bf16)a0.w,
                     (__bf16)a1.x, (__bf16)a1.y, (__bf16)a1.z, (__bf16)a1.w};
        *(bf16x8*)(k1 + (size_t)e*64 + off + v*8) = pk;
    }
}

// Layer 2 of kernel MLP as MFMA GEMM: [E,64] x [64,128] + b2, relu -> kbf [E,128] bf16.
// 4 independent waves per block, 64 edges per wave.
__global__ __launch_bounds__(256, 2)
void k_edge2(const __bf16* __restrict__ k1, const __bf16* __restrict__ w2sw,
             const float* __restrict__ b2, __bf16* __restrict__ kbf) {
    const int lane = threadIdx.x & 63;
    const int wave = threadIdx.x >> 6;
    const int q = lane >> 4, t = lane & 15;
    const int base = blockIdx.x * 256 + wave * 64;

    bf16x8 af[4][2];
    #pragma unroll
    for (int mt = 0; mt < 4; ++mt) {
        int ea = base + mt*16 + t;
        ea = ea < NE ? ea : NE - 1;
        const __bf16* kr = k1 + (size_t)ea * 64 + q * 8;
        af[mt][0] = *(const bf16x8*)(kr);
        af[mt][1] = *(const bf16x8*)(kr + 32);
    }

    for (int nt = 0; nt < 8; ++nt) {
        f32x4 acc[4];
        #pragma unroll
        for (int mt = 0; mt < 4; ++mt) acc[mt] = (f32x4){0.f, 0.f, 0.f, 0.f};
        #pragma unroll
        for (int ks = 0; ks < 2; ++ks) {
            bf16x8 bf = *(const bf16x8*)(w2sw + ((nt*2 + ks)*64 + lane) * 8);
            #pragma unroll
            for (int mt = 0; mt < 4; ++mt)
                acc[mt] = __builtin_amdgcn_mfma_f32_16x16x32_bf16(af[mt][ks], bf, acc[mt], 0, 0, 0);
        }
        float bias = b2[nt*16 + t];
        #pragma unroll
        for (int mt = 0; mt < 4; ++mt) {
            #pragma unroll
            for (int r = 0; r < 4; ++r) {
                int e = base + mt*16 + q*4 + r;
                if (e < NE)
                    kbf[(size_t)e*128 + nt*16 + t] = (__bf16)fmaxf(acc[mt][r] + bias, 0.f);
            }
        }
    }
}

// Fused: big GEMM (E x 128 x 1024) with einsum epilogue -> m[e][i] in regs,
// then phi MLP + atomic scatter. 4 waves per block, 64 edges per wave.
__global__ __launch_bounds__(256, 4)
void k_gemm(const __bf16* __restrict__ kbf, const __bf16* __restrict__ w3sw,
            const float* __restrict__ b3, const float* __restrict__ h,
            const int* __restrict__ eidx, const float* __restrict__ cd4,
            const float* __restrict__ cm_w1, const float* __restrict__ cm_b1,
            const float* __restrict__ cm_w2,
            float* __restrict__ acc_coord, float* __restrict__ acc_m) {
    __shared__ float wk[4][64 * 36];       // stride 36: 16B-aligned rows, 2-way max conflict
    const int lane = threadIdx.x & 63;
    const int wave = threadIdx.x >> 6;
    const int q = lane >> 4, t = lane & 15;
    const int base = blockIdx.x * 256 + wave * 64;
    float* wkw = wk[wave];

    // gather h[col] for this lane's edge into registers
    int eg = base + lane;
    int egc = eg < NE ? eg : NE - 1;
    int col = eidx[NE + egc];
    float hcol[32];
    const f32x4* hp = (const f32x4*)(h + (size_t)col * 32);
    #pragma unroll
    for (int v = 0; v < 8; ++v) {
        f32x4 hv = hp[v];
        hcol[v*4+0] = hv.x; hcol[v*4+1] = hv.y; hcol[v*4+2] = hv.z; hcol[v*4+3] = hv.w;
    }

    // A fragments: lane supplies A[m=t][k=q*8..q*8+7] for 4 M-tiles x 4 K-steps
    bf16x8 afrag[4][4];
    #pragma unroll
    for (int mt = 0; mt < 4; ++mt) {
        int ea = base + mt*16 + t;
        ea = ea < NE ? ea : NE - 1;
        const __bf16* kr = kbf + (size_t)ea * 128 + q * 8;
        #pragma unroll
        for (int ks = 0; ks < 4; ++ks)
            afrag[mt][ks] = *(const bf16x8*)(kr + ks * 32);
    }

    const bool wvalid = eg < NE;
    const float* wkrow = wkw + lane * 36;  // lane*144B, 16B aligned -> b128 reads
    float mv[32];

    for (int i = 0; i < 32; ++i) {
        f32x4 acc[4][2];
        #pragma unroll
        for (int mt = 0; mt < 4; ++mt) {
            acc[mt][0] = (f32x4){0.f, 0.f, 0.f, 0.f};
            acc[mt][1] = (f32x4){0.f, 0.f, 0.f, 0.f};
        }
        const __bf16* wb = w3sw + (size_t)i * 4096;
        #pragma unroll
        for (int jt = 0; jt < 2; ++jt) {
            #pragma unroll
            for (int ks = 0; ks < 4; ++ks) {
                bf16x8 bfrag = *(const bf16x8*)(wb + ((jt*4 + ks)*64 + lane) * 8);
                #pragma unroll
                for (int mt = 0; mt < 4; ++mt)
                    acc[mt][jt] = __builtin_amdgcn_mfma_f32_16x16x32_bf16(
                        afrag[mt][ks], bfrag, acc[mt][jt], 0, 0, 0);
            }
        }
        float bias0 = b3[i*32 + t];
        float bias1 = b3[i*32 + 16 + t];
        __syncthreads();   // prev iteration's reads done
        #pragma unroll
        for (int mt = 0; mt < 4; ++mt) {
            #pragma unroll
            for (int r = 0; r < 4; ++r) {
                int row = mt*16 + q*4 + r;
                wkw[row*36 + t]      = acc[mt][0][r] + bias0;
                wkw[row*36 + 16 + t] = acc[mt][1][r] + bias1;
            }
        }
        __syncthreads();
        float s = 0.f;
        #pragma unroll
        for (int v = 0; v < 8; ++v) {
            f32x4 wv = *(const f32x4*)(wkrow + v*4);
            s += wv.x*hcol[v*4+0] + wv.y*hcol[v*4+1] + wv.z*hcol[v*4+2] + wv.w*hcol[v*4+3];
        }
        mv[i] = s;
    }

    // ---- fused phi MLP (32 -> 32 relu -> 1) ----
    float phi = 0.f;
    for (int o = 0; o < 32; o += 4) {
        f32x4 a = *(const f32x4*)(cm_b1 + o);
        #pragma unroll
        for (int i = 0; i < 32; ++i)
            a += mv[i] * (*(const f32x4*)(cm_w1 + i*32 + o));
        a = relu4(a);
        f32x4 w2 = *(const f32x4*)(cm_w2 + o);
        phi += a.x*w2.x + a.y*w2.y + a.z*w2.z + a.w*w2.w;
    }

    if (wvalid) {
        int r = eidx[eg];
        f32x4 cd = *(const f32x4*)(cd4 + (size_t)eg*4);
        atomicAdd(&acc_coord[r*3+0], cd.x * phi);
        atomicAdd(&acc_coord[r*3+1], cd.y * phi);
        atomicAdd(&acc_coord[r*3+2], cd.z * phi);
        float* am = acc_m + (size_t)r * 32;
        #pragma unroll
        for (int i = 0; i < 32; ++i) atomicAdd(&am[i], mv[i]);
    }
}

__global__ void k_node(const float* __restrict__ acc_coord, const float* __restrict__ acc_m,
                       const float* __restrict__ deg_inv,
                       float* __restrict__ coord, float* __restrict__ h) {
    int n = blockIdx.x * blockDim.x + threadIdx.x;
    if (n >= NN) return;
    float di = deg_inv[n];
    coord[n*3+0] += acc_coord[n*3+0] * di;
    coord[n*3+1] += acc_coord[n*3+1] * di;
    coord[n*3+2] += acc_coord[n*3+2] * di;
    #pragma unroll
    for (int j = 0; j < 32; j += 4) {
        f32x4 hv = *(const f32x4*)(h + n*32 + j);
        f32x4 av = *(const f32x4*)(acc_m + n*32 + j);
        hv = relu4(hv + av * di);
        *(f32x4*)(h + n*32 + j) = hv;
    }
}

__global__ __launch_bounds__(256, 4)
void k_final(const float* __restrict__ h, const float* __restrict__ coord,
             const float* __restrict__ fw1, const float* __restrict__ fb1,
             const float* __restrict__ fw2, const float* __restrict__ fb2,
             float* __restrict__ out) {
    int n = blockIdx.x * blockDim.x + threadIdx.x;
    if (n >= NN) return;
    float hreg[32];
    #pragma unroll
    for (int i = 0; i < 32; ++i) hreg[i] = h[n*32 + i];
    float ov = fb2[0];
    for (int o = 0; o < 64; o += 4) {
        f32x4 a = *(const f32x4*)(fb1 + o);
        #pragma unroll
        for (int i = 0; i < 32; ++i)
            a += hreg[i] * (*(const f32x4*)(fw1 + i*64 + o));
        a = relu4(a);
        f32x4 w2 = *(const f32x4*)(fw2 + o);
        ov += a.x*w2.x + a.y*w2.y + a.z*w2.z + a.w*w2.w;
    }
    out[n] = ov;                       // output 0: [N,1]
    out[NN + n*3 + 0] = coord[n*3+0];  // output 1: coord [N,3]
    out[NN + n*3 + 1] = coord[n*3+1];
    out[NN + n*3 + 2] = coord[n*3+2];
}

// ---------------- launch ----------------

extern "C" void kernel_launch(void* const* d_in, const int* in_sizes, int n_in,
                              void* d_out, int out_size, void* d_ws, size_t ws_size,
                              hipStream_t stream) {
    const float* x      = (const float*)d_in[0];
    const int*   eidx   = (const int*)  d_in[1];
    const float* eattr  = (const float*)d_in[2];
    const float* cinit  = (const float*)d_in[3];
    const float* fc1w   = (const float*)d_in[4];
    const float* fc1b   = (const float*)d_in[5];
    const float* kw1    = (const float*)d_in[6];
    const float* kb1    = (const float*)d_in[7];
    const float* kw2    = (const float*)d_in[8];
    const float* kb2    = (const float*)d_in[9];
    const float* kw3    = (const float*)d_in[10];
    const float* kb3    = (const float*)d_in[11];
    const float* cmw1   = (const float*)d_in[12];
    const float* cmb1   = (const float*)d_in[13];
    const float* cmw2   = (const float*)d_in[14];
    const float* f2w1   = (const float*)d_in[15];
    const float* f2b1   = (const float*)d_in[16];
    const float* f2w2   = (const float*)d_in[17];
    const float* f2b2   = (const float*)d_in[18];
    float* out = (float*)d_out;

    // workspace carve-up (256B aligned slots)
    char* p = (char*)d_ws;
    auto carve = [&](size_t bytes) {
        void* r = (void*)p;
        p += (bytes + 255) & ~(size_t)255;
        return r;
    };
    float*  h        = (float*) carve((size_t)NN * 32 * 4);
    float*  coord    = (float*) carve((size_t)NN * 3 * 4);
    int*    deg      = (int*)   carve((size_t)NN * 4);
    float*  deg_inv  = (float*) carve((size_t)NN * 4);
    float*  acc      = (float*) carve((size_t)NN * 35 * 4);  // [N*3 coord | N*32 m]
    float*  cd4      = (float*) carve((size_t)NE * 4 * 4);
    __bf16* k1       = (__bf16*)carve((size_t)NE * 64 * 2);
    __bf16* kbf      = (__bf16*)carve((size_t)NE * 128 * 2);
    __bf16* w3sw     = (__bf16*)carve((size_t)131072 * 2);
    __bf16* w2sw     = (__bf16*)carve((size_t)8192 * 2);
    float*  acc_c    = acc;
    float*  acc_m    = acc + (size_t)NN * 3;

    const int TB = 256;
    dim3 gE((NE + TB - 1) / TB), gN((NN + TB - 1) / TB), b(TB);
    dim3 gE2((2*NE + TB - 1) / TB);          // 2 threads per edge
    dim3 gW((NE + 255) / 256);               // 4 waves x 64 edges per block

    hipMemsetAsync(deg, 0, (size_t)NN * 4, stream);
    k_deg <<<gE, b, 0, stream>>>(eidx, deg);
    k_init<<<gN, b, 0, stream>>>(x, fc1w, fc1b, cinit, deg, h, coord, deg_inv);
    k_w3sw<<<512, b, 0, stream>>>(kw3, w3sw);
    k_w2sw<<<32, b, 0, stream>>>(kw2, w2sw);

    for (int d = 0; d < 3; ++d) {
        hipMemsetAsync(acc, 0, (size_t)NN * 35 * 4, stream);
        k_edge1<<<gE2, b, 0, stream>>>(coord, eidx, eattr, kw1, kb1, cd4, k1);
        k_edge2<<<gW, b, 0, stream>>>(k1, w2sw, kb2, kbf);
        k_gemm <<<gW, b, 0, stream>>>(
            kbf, w3sw, kb3, h, eidx, cd4, cmw1, cmb1, cmw2, acc_c, acc_m);
        k_node<<<gN, b, 0, stream>>>(acc_c, acc_m, deg_inv, coord, h);
    }
    k_final<<<gN, b, 0, stream>>>(h, coord, f2w1, f2b1, f2w2, f2b2, out);
}

// Round 5
// 1016.060 us; speedup vs baseline: 3.4914x; 1.6956x over previous
//
#include <hip/hip_runtime.h>
#include <hip/hip_bf16.h>

#define NN 10000
#define NE 100000

typedef __bf16 bf16x8 __attribute__((ext_vector_type(8)));
typedef __bf16 bf16x4 __attribute__((ext_vector_type(4)));
typedef float  f32x4  __attribute__((ext_vector_type(4)));

__device__ __forceinline__ f32x4 relu4(f32x4 a) {
    a.x = fmaxf(a.x, 0.f); a.y = fmaxf(a.y, 0.f);
    a.z = fmaxf(a.z, 0.f); a.w = fmaxf(a.w, 0.f);
    return a;
}

// ---------------- one-time kernels ----------------

__global__ void k_deg(const int* __restrict__ eidx, int* __restrict__ deg) {
    int e = blockIdx.x * blockDim.x + threadIdx.x;
    if (e < NE) atomicAdd(&deg[eidx[e]], 1);
}

__global__ void k_init(const float* __restrict__ x, const float* __restrict__ fc1w,
                       const float* __restrict__ fc1b, const float* __restrict__ cinit,
                       const int* __restrict__ deg,
                       float* __restrict__ h, float* __restrict__ coord,
                       float* __restrict__ deg_inv) {
    int n = blockIdx.x * blockDim.x + threadIdx.x;
    if (n >= NN) return;
    float x0 = x[n*3+0], x1 = x[n*3+1], x2 = x[n*3+2];
    #pragma unroll
    for (int j = 0; j < 32; j += 4) {
        f32x4 a = *(const f32x4*)(fc1b + j);
        a += x0 * (*(const f32x4*)(fc1w + 0*32 + j));
        a += x1 * (*(const f32x4*)(fc1w + 1*32 + j));
        a += x2 * (*(const f32x4*)(fc1w + 2*32 + j));
        *(f32x4*)(h + n*32 + j) = a;   // no relu on fc1 (matches reference)
    }
    coord[n*3+0] = cinit[n*3+0];
    coord[n*3+1] = cinit[n*3+1];
    coord[n*3+2] = cinit[n*3+2];
    int d = deg[n];
    deg_inv[n] = 1.0f / (float)(d > 1 ? d : 1);
}

// Swizzle ker_w3 [128,1024] fp32 -> bf16 in MFMA-B fragment order.
__global__ void k_w3sw(const float* __restrict__ w3, __bf16* __restrict__ w3sw) {
    int t = blockIdx.x * blockDim.x + threadIdx.x;   // 0 .. 131071
    int jj = t & 7;
    int L  = (t >> 3) & 63;
    int ks = (t >> 9) & 3;
    int jt = (t >> 11) & 1;
    int i  = t >> 12;
    int c    = ks*32 + (L >> 4)*8 + jj;              // K index 0..127
    int colv = i*32 + jt*16 + (L & 15);              // output col 0..1023
    w3sw[t] = (__bf16)w3[c*1024 + colv];
}

// Swizzle ker_w2 [64,128] fp32 -> bf16 in MFMA-B fragment order (K=64 -> 2 k-steps).
__global__ void k_w2sw(const float* __restrict__ w2, __bf16* __restrict__ w2sw) {
    int t = blockIdx.x * blockDim.x + threadIdx.x;   // 0 .. 8191
    if (t >= 8192) return;
    int jj = t & 7;
    int L  = (t >> 3) & 63;
    int ks = (t >> 9) & 1;
    int nt = t >> 10;                                // 0..7
    int c1 = ks*32 + (L >> 4)*8 + jj;                // K index 0..63
    int c2 = nt*16 + (L & 15);                       // output col 0..127
    w2sw[t] = (__bf16)w2[c1*128 + c2];
}

// ---------------- per-layer kernels ----------------

// Layer 1 of kernel MLP: 2 threads per edge, each computes 32 of 64 channels.
__global__ void k_edge1(const float* __restrict__ coord, const int* __restrict__ eidx,
                        const float* __restrict__ eattr,
                        const float* __restrict__ w1, const float* __restrict__ b1,
                        float* __restrict__ cd4, __bf16* __restrict__ k1) {
    int tid = blockIdx.x * blockDim.x + threadIdx.x;
    int e = tid >> 1, hf = tid & 1;
    if (e >= NE) return;
    int r = eidx[e], c = eidx[NE + e];
    float dx = coord[r*3+0] - coord[c*3+0];
    float dy = coord[r*3+1] - coord[c*3+1];
    float dz = coord[r*3+2] - coord[c*3+2];
    float rad = dx*dx + dy*dy + dz*dz;
    if (hf == 0) {
        f32x4 cdv = {dx, dy, dz, rad};
        *(f32x4*)(cd4 + (size_t)e*4) = cdv;
    }
    float kin[7];
    #pragma unroll
    for (int a = 0; a < 6; ++a) kin[a] = eattr[(size_t)e*6 + a];
    kin[6] = rad;

    const int off = hf * 32;
    f32x4 acc[8];
    #pragma unroll
    for (int g = 0; g < 8; ++g) acc[g] = *(const f32x4*)(b1 + off + g*4);
    #pragma unroll
    for (int t = 0; t < 7; ++t) {
        float kv = kin[t];
        #pragma unroll
        for (int g = 0; g < 8; ++g)
            acc[g] += kv * (*(const f32x4*)(w1 + t*64 + off + g*4));
    }
    #pragma unroll
    for (int v = 0; v < 4; ++v) {
        f32x4 a0 = relu4(acc[2*v]), a1 = relu4(acc[2*v+1]);
        bf16x8 pk = {(__bf16)a0.x, (__bf16)a0.y, (__bf16)a0.z, (__bf16)a0.w,
                     (__bf16)a1.x, (__bf16)a1.y, (__bf16)a1.z, (__bf16)a1.w};
        *(bf16x8*)(k1 + (size_t)e*64 + off + v*8) = pk;
    }
}

// Layer 2 of kernel MLP as MFMA GEMM: [E,64] x [64,128] + b2, relu -> kbf [E,128] bf16.
__global__ __launch_bounds__(256, 2)
void k_edge2(const __bf16* __restrict__ k1, const __bf16* __restrict__ w2sw,
             const float* __restrict__ b2, __bf16* __restrict__ kbf) {
    const int lane = threadIdx.x & 63;
    const int wave = threadIdx.x >> 6;
    const int q = lane >> 4, t = lane & 15;
    const int base = blockIdx.x * 256 + wave * 64;

    bf16x8 af[4][2];
    #pragma unroll
    for (int mt = 0; mt < 4; ++mt) {
        int ea = base + mt*16 + t;
        ea = ea < NE ? ea : NE - 1;
        const __bf16* kr = k1 + (size_t)ea * 64 + q * 8;
        af[mt][0] = *(const bf16x8*)(kr);
        af[mt][1] = *(const bf16x8*)(kr + 32);
    }

    for (int nt = 0; nt < 8; ++nt) {
        f32x4 acc[4];
        #pragma unroll
        for (int mt = 0; mt < 4; ++mt) acc[mt] = (f32x4){0.f, 0.f, 0.f, 0.f};
        #pragma unroll
        for (int ks = 0; ks < 2; ++ks) {
            bf16x8 bf = *(const bf16x8*)(w2sw + ((nt*2 + ks)*64 + lane) * 8);
            #pragma unroll
            for (int mt = 0; mt < 4; ++mt)
                acc[mt] = __builtin_amdgcn_mfma_f32_16x16x32_bf16(af[mt][ks], bf, acc[mt], 0, 0, 0);
        }
        float bias = b2[nt*16 + t];
        #pragma unroll
        for (int mt = 0; mt < 4; ++mt) {
            #pragma unroll
            for (int r = 0; r < 4; ++r) {
                int e = base + mt*16 + q*4 + r;
                if (e < NE)
                    kbf[(size_t)e*128 + nt*16 + t] = (__bf16)fmaxf(acc[mt][r] + bias, 0.f);
            }
        }
    }
}

// Fused: big GEMM (E x 128 x 1024) with einsum epilogue -> m[e][i] in regs,
// then phi MLP + atomic scatter. ONE 64-lane wave per block.
// __launch_bounds__(64,2): <=256 VGPR budget -> the ~190-reg live set
// (afrag 64 + hcol 32 + mv 32 + acc 32) fits WITHOUT spill.
// (round4's (256,4) capped it at 64 VGPR -> 880 MB scratch traffic = 488 us.)
__global__ __launch_bounds__(64, 2)
void k_gemm(const __bf16* __restrict__ kbf, const __bf16* __restrict__ w3sw,
            const float* __restrict__ b3, const float* __restrict__ h,
            const int* __restrict__ eidx, const float* __restrict__ cd4,
            const float* __restrict__ cm_w1, const float* __restrict__ cm_b1,
            const float* __restrict__ cm_w2,
            float* __restrict__ acc_coord, float* __restrict__ acc_m) {
    __shared__ float wk[64 * 36];          // stride 36: 16B-aligned rows, 0 measured conflicts
    const int lane = threadIdx.x;          // 0..63
    const int q = lane >> 4, t = lane & 15;
    const int base = blockIdx.x * 64;

    // gather h[col] for this lane's edge into registers
    int eg = base + lane;
    int egc = eg < NE ? eg : NE - 1;
    int col = eidx[NE + egc];
    float hcol[32];
    const f32x4* hp = (const f32x4*)(h + (size_t)col * 32);
    #pragma unroll
    for (int v = 0; v < 8; ++v) {
        f32x4 hv = hp[v];
        hcol[v*4+0] = hv.x; hcol[v*4+1] = hv.y; hcol[v*4+2] = hv.z; hcol[v*4+3] = hv.w;
    }

    // A fragments: lane supplies A[m=t][k=q*8..q*8+7] for 4 M-tiles x 4 K-steps
    bf16x8 afrag[4][4];
    #pragma unroll
    for (int mt = 0; mt < 4; ++mt) {
        int ea = base + mt*16 + t;
        ea = ea < NE ? ea : NE - 1;
        const __bf16* kr = kbf + (size_t)ea * 128 + q * 8;
        #pragma unroll
        for (int ks = 0; ks < 4; ++ks)
            afrag[mt][ks] = *(const bf16x8*)(kr + ks * 32);
    }

    const bool wvalid = eg < NE;
    const float* wkrow = wk + lane * 36;   // 144B stride, 16B aligned -> b128 reads
    float mv[32];

    for (int i = 0; i < 32; ++i) {
        f32x4 acc[4][2];
        #pragma unroll
        for (int mt = 0; mt < 4; ++mt) {
            acc[mt][0] = (f32x4){0.f, 0.f, 0.f, 0.f};
            acc[mt][1] = (f32x4){0.f, 0.f, 0.f, 0.f};
        }
        const __bf16* wb = w3sw + (size_t)i * 4096;
        #pragma unroll
        for (int jt = 0; jt < 2; ++jt) {
            #pragma unroll
            for (int ks = 0; ks < 4; ++ks) {
                bf16x8 bfrag = *(const bf16x8*)(wb + ((jt*4 + ks)*64 + lane) * 8);
                #pragma unroll
                for (int mt = 0; mt < 4; ++mt)
                    acc[mt][jt] = __builtin_amdgcn_mfma_f32_16x16x32_bf16(
                        afrag[mt][ks], bfrag, acc[mt][jt], 0, 0, 0);
            }
        }
        float bias0 = b3[i*32 + t];
        float bias1 = b3[i*32 + 16 + t];
        __syncthreads();   // prev iteration's reads done
        #pragma unroll
        for (int mt = 0; mt < 4; ++mt) {
            #pragma unroll
            for (int r = 0; r < 4; ++r) {
                int row = mt*16 + q*4 + r;
                wk[row*36 + t]      = acc[mt][0][r] + bias0;
                wk[row*36 + 16 + t] = acc[mt][1][r] + bias1;
            }
        }
        __syncthreads();
        float s = 0.f;
        #pragma unroll
        for (int v = 0; v < 8; ++v) {
            f32x4 wv = *(const f32x4*)(wkrow + v*4);
            s += wv.x*hcol[v*4+0] + wv.y*hcol[v*4+1] + wv.z*hcol[v*4+2] + wv.w*hcol[v*4+3];
        }
        mv[i] = s;
    }

    // ---- fused phi MLP (32 -> 32 relu -> 1) ----
    float phi = 0.f;
    for (int o = 0; o < 32; o += 4) {
        f32x4 a = *(const f32x4*)(cm_b1 + o);
        #pragma unroll
        for (int i = 0; i < 32; ++i)
            a += mv[i] * (*(const f32x4*)(cm_w1 + i*32 + o));
        a = relu4(a);
        f32x4 w2 = *(const f32x4*)(cm_w2 + o);
        phi += a.x*w2.x + a.y*w2.y + a.z*w2.z + a.w*w2.w;
    }

    if (wvalid) {
        int r = eidx[eg];
        f32x4 cd = *(const f32x4*)(cd4 + (size_t)eg*4);
        atomicAdd(&acc_coord[r*3+0], cd.x * phi);
        atomicAdd(&acc_coord[r*3+1], cd.y * phi);
        atomicAdd(&acc_coord[r*3+2], cd.z * phi);
        float* am = acc_m + (size_t)r * 32;
        #pragma unroll
        for (int i = 0; i < 32; ++i) atomicAdd(&am[i], mv[i]);
    }
}

__global__ void k_node(const float* __restrict__ acc_coord, const float* __restrict__ acc_m,
                       const float* __restrict__ deg_inv,
                       float* __restrict__ coord, float* __restrict__ h) {
    int n = blockIdx.x * blockDim.x + threadIdx.x;
    if (n >= NN) return;
    float di = deg_inv[n];
    coord[n*3+0] += acc_coord[n*3+0] * di;
    coord[n*3+1] += acc_coord[n*3+1] * di;
    coord[n*3+2] += acc_coord[n*3+2] * di;
    #pragma unroll
    for (int j = 0; j < 32; j += 4) {
        f32x4 hv = *(const f32x4*)(h + n*32 + j);
        f32x4 av = *(const f32x4*)(acc_m + n*32 + j);
        hv = relu4(hv + av * di);
        *(f32x4*)(h + n*32 + j) = hv;
    }
}

__global__ __launch_bounds__(256, 4)
void k_final(const float* __restrict__ h, const float* __restrict__ coord,
             const float* __restrict__ fw1, const float* __restrict__ fb1,
             const float* __restrict__ fw2, const float* __restrict__ fb2,
             float* __restrict__ out) {
    int n = blockIdx.x * blockDim.x + threadIdx.x;
    if (n >= NN) return;
    float hreg[32];
    #pragma unroll
    for (int i = 0; i < 32; ++i) hreg[i] = h[n*32 + i];
    float ov = fb2[0];
    for (int o = 0; o < 64; o += 4) {
        f32x4 a = *(const f32x4*)(fb1 + o);
        #pragma unroll
        for (int i = 0; i < 32; ++i)
            a += hreg[i] * (*(const f32x4*)(fw1 + i*64 + o));
        a = relu4(a);
        f32x4 w2 = *(const f32x4*)(fw2 + o);
        ov += a.x*w2.x + a.y*w2.y + a.z*w2.z + a.w*w2.w;
    }
    out[n] = ov;                       // output 0: [N,1]
    out[NN + n*3 + 0] = coord[n*3+0];  // output 1: coord [N,3]
    out[NN + n*3 + 1] = coord[n*3+1];
    out[NN + n*3 + 2] = coord[n*3+2];
}

// ---------------- launch ----------------

extern "C" void kernel_launch(void* const* d_in, const int* in_sizes, int n_in,
                              void* d_out, int out_size, void* d_ws, size_t ws_size,
                              hipStream_t stream) {
    const float* x      = (const float*)d_in[0];
    const int*   eidx   = (const int*)  d_in[1];
    const float* eattr  = (const float*)d_in[2];
    const float* cinit  = (const float*)d_in[3];
    const float* fc1w   = (const float*)d_in[4];
    const float* fc1b   = (const float*)d_in[5];
    const float* kw1    = (const float*)d_in[6];
    const float* kb1    = (const float*)d_in[7];
    const float* kw2    = (const float*)d_in[8];
    const float* kb2    = (const float*)d_in[9];
    const float* kw3    = (const float*)d_in[10];
    const float* kb3    = (const float*)d_in[11];
    const float* cmw1   = (const float*)d_in[12];
    const float* cmb1   = (const float*)d_in[13];
    const float* cmw2   = (const float*)d_in[14];
    const float* f2w1   = (const float*)d_in[15];
    const float* f2b1   = (const float*)d_in[16];
    const float* f2w2   = (const float*)d_in[17];
    const float* f2b2   = (const float*)d_in[18];
    float* out = (float*)d_out;

    // workspace carve-up (256B aligned slots)
    char* p = (char*)d_ws;
    auto carve = [&](size_t bytes) {
        void* r = (void*)p;
        p += (bytes + 255) & ~(size_t)255;
        return r;
    };
    float*  h        = (float*) carve((size_t)NN * 32 * 4);
    float*  coord    = (float*) carve((size_t)NN * 3 * 4);
    int*    deg      = (int*)   carve((size_t)NN * 4);
    float*  deg_inv  = (float*) carve((size_t)NN * 4);
    float*  acc      = (float*) carve((size_t)NN * 35 * 4);  // [N*3 coord | N*32 m]
    float*  cd4      = (float*) carve((size_t)NE * 4 * 4);
    __bf16* k1       = (__bf16*)carve((size_t)NE * 64 * 2);
    __bf16* kbf      = (__bf16*)carve((size_t)NE * 128 * 2);
    __bf16* w3sw     = (__bf16*)carve((size_t)131072 * 2);
    __bf16* w2sw     = (__bf16*)carve((size_t)8192 * 2);
    float*  acc_c    = acc;
    float*  acc_m    = acc + (size_t)NN * 3;

    const int TB = 256;
    dim3 gE((NE + TB - 1) / TB), gN((NN + TB - 1) / TB), b(TB);
    dim3 gE2((2*NE + TB - 1) / TB);          // 2 threads per edge
    dim3 gW((NE + 255) / 256);               // 4 waves x 64 edges per block
    dim3 gG((NE + 63) / 64);                 // 1 wave x 64 edges per block

    hipMemsetAsync(deg, 0, (size_t)NN * 4, stream);
    k_deg <<<gE, b, 0, stream>>>(eidx, deg);
    k_init<<<gN, b, 0, stream>>>(x, fc1w, fc1b, cinit, deg, h, coord, deg_inv);
    k_w3sw<<<512, b, 0, stream>>>(kw3, w3sw);
    k_w2sw<<<32, b, 0, stream>>>(kw2, w2sw);

    for (int d = 0; d < 3; ++d) {
        hipMemsetAsync(acc, 0, (size_t)NN * 35 * 4, stream);
        k_edge1<<<gE2, b, 0, stream>>>(coord, eidx, eattr, kw1, kb1, cd4, k1);
        k_edge2<<<gW, b, 0, stream>>>(k1, w2sw, kb2, kbf);
        k_gemm <<<gG, dim3(64), 0, stream>>>(
            kbf, w3sw, kb3, h, eidx, cd4, cmw1, cmb1, cmw2, acc_c, acc_m);
        k_node<<<gN, b, 0, stream>>>(acc_c, acc_m, deg_inv, coord, h);
    }
    k_final<<<gN, b, 0, stream>>>(h, coord, f2w1, f2b1, f2w2, f2b2, out);
}

// Round 6
// 575.190 us; speedup vs baseline: 6.1675x; 1.7665x over previous
//
#include <hip/hip_runtime.h>
#include <hip/hip_bf16.h>

#define NN 10000
#define NE 100000

typedef __bf16 bf16x8 __attribute__((ext_vector_type(8)));
typedef __bf16 bf16x4 __attribute__((ext_vector_type(4)));
typedef float  f32x4  __attribute__((ext_vector_type(4)));

__device__ __forceinline__ f32x4 relu4(f32x4 a) {
    a.x = fmaxf(a.x, 0.f); a.y = fmaxf(a.y, 0.f);
    a.z = fmaxf(a.z, 0.f); a.w = fmaxf(a.w, 0.f);
    return a;
}

// ---------------- one-time kernels ----------------

__global__ void k_deg(const int* __restrict__ eidx, int* __restrict__ deg) {
    int e = blockIdx.x * blockDim.x + threadIdx.x;
    if (e < NE) atomicAdd(&deg[eidx[e]], 1);
}

// Single-block exclusive scan over deg -> rowptr[NN+1], cursor copy.
__global__ void k_scan(const int* __restrict__ deg, int* __restrict__ rowptr,
                       int* __restrict__ cursor) {
    __shared__ int ssum[256];
    const int tid = threadIdx.x;
    const int CH = 40;                       // 256*40 >= 10000
    const int base = tid * CH;
    int s = 0;
    for (int i = 0; i < CH; ++i) { int n = base + i; if (n < NN) s += deg[n]; }
    ssum[tid] = s;
    __syncthreads();
    for (int off = 1; off < 256; off <<= 1) {
        int t = (tid >= off) ? ssum[tid - off] : 0;
        __syncthreads();
        ssum[tid] += t;
        __syncthreads();
    }
    int run = ssum[tid] - s;                 // exclusive prefix
    for (int i = 0; i < CH; ++i) {
        int n = base + i;
        if (n < NN) { rowptr[n] = run; cursor[n] = run; run += deg[n]; }
    }
    if (tid == 255) rowptr[NN] = ssum[255];
}

__global__ void k_fill(const int* __restrict__ eidx, int* __restrict__ cursor,
                       int* __restrict__ ebyrow) {
    int e = blockIdx.x * blockDim.x + threadIdx.x;
    if (e < NE) {
        int r = eidx[e];
        int slot = atomicAdd(&cursor[r], 1);
        ebyrow[slot] = e;
    }
}

__global__ void k_init(const float* __restrict__ x, const float* __restrict__ fc1w,
                       const float* __restrict__ fc1b, const float* __restrict__ cinit,
                       const int* __restrict__ deg,
                       float* __restrict__ h, float* __restrict__ coord,
                       float* __restrict__ deg_inv) {
    int n = blockIdx.x * blockDim.x + threadIdx.x;
    if (n >= NN) return;
    float x0 = x[n*3+0], x1 = x[n*3+1], x2 = x[n*3+2];
    #pragma unroll
    for (int j = 0; j < 32; j += 4) {
        f32x4 a = *(const f32x4*)(fc1b + j);
        a += x0 * (*(const f32x4*)(fc1w + 0*32 + j));
        a += x1 * (*(const f32x4*)(fc1w + 1*32 + j));
        a += x2 * (*(const f32x4*)(fc1w + 2*32 + j));
        *(f32x4*)(h + n*32 + j) = a;   // no relu on fc1 (matches reference)
    }
    coord[n*3+0] = cinit[n*3+0];
    coord[n*3+1] = cinit[n*3+1];
    coord[n*3+2] = cinit[n*3+2];
    int d = deg[n];
    deg_inv[n] = 1.0f / (float)(d > 1 ? d : 1);
}

// Swizzle ker_w3 [128,1024] fp32 -> bf16 in MFMA-B fragment order.
__global__ void k_w3sw(const float* __restrict__ w3, __bf16* __restrict__ w3sw) {
    int t = blockIdx.x * blockDim.x + threadIdx.x;   // 0 .. 131071
    int jj = t & 7;
    int L  = (t >> 3) & 63;
    int ks = (t >> 9) & 3;
    int jt = (t >> 11) & 1;
    int i  = t >> 12;
    int c    = ks*32 + (L >> 4)*8 + jj;              // K index 0..127
    int colv = i*32 + jt*16 + (L & 15);              // output col 0..1023
    w3sw[t] = (__bf16)w3[c*1024 + colv];
}

// Swizzle ker_w2 [64,128] fp32 -> bf16 in MFMA-B fragment order (K=64 -> 2 k-steps).
__global__ void k_w2sw(const float* __restrict__ w2, __bf16* __restrict__ w2sw) {
    int t = blockIdx.x * blockDim.x + threadIdx.x;   // 0 .. 8191
    if (t >= 8192) return;
    int jj = t & 7;
    int L  = (t >> 3) & 63;
    int ks = (t >> 9) & 1;
    int nt = t >> 10;                                // 0..7
    int c1 = ks*32 + (L >> 4)*8 + jj;                // K index 0..63
    int c2 = nt*16 + (L & 15);                       // output col 0..127
    w2sw[t] = (__bf16)w2[c1*128 + c2];
}

// ---------------- per-layer kernels ----------------

// Layer 1 of kernel MLP: 2 threads per edge, each computes 32 of 64 channels.
__global__ void k_edge1(const float* __restrict__ coord, const int* __restrict__ eidx,
                        const float* __restrict__ eattr,
                        const float* __restrict__ w1, const float* __restrict__ b1,
                        float* __restrict__ cd4, __bf16* __restrict__ k1) {
    int tid = blockIdx.x * blockDim.x + threadIdx.x;
    int e = tid >> 1, hf = tid & 1;
    if (e >= NE) return;
    int r = eidx[e], c = eidx[NE + e];
    float dx = coord[r*3+0] - coord[c*3+0];
    float dy = coord[r*3+1] - coord[c*3+1];
    float dz = coord[r*3+2] - coord[c*3+2];
    float rad = dx*dx + dy*dy + dz*dz;
    if (hf == 0) {
        f32x4 cdv = {dx, dy, dz, rad};
        *(f32x4*)(cd4 + (size_t)e*4) = cdv;
    }
    float kin[7];
    #pragma unroll
    for (int a = 0; a < 6; ++a) kin[a] = eattr[(size_t)e*6 + a];
    kin[6] = rad;

    const int off = hf * 32;
    f32x4 acc[8];
    #pragma unroll
    for (int g = 0; g < 8; ++g) acc[g] = *(const f32x4*)(b1 + off + g*4);
    #pragma unroll
    for (int t = 0; t < 7; ++t) {
        float kv = kin[t];
        #pragma unroll
        for (int g = 0; g < 8; ++g)
            acc[g] += kv * (*(const f32x4*)(w1 + t*64 + off + g*4));
    }
    #pragma unroll
    for (int v = 0; v < 4; ++v) {
        f32x4 a0 = relu4(acc[2*v]), a1 = relu4(acc[2*v+1]);
        bf16x8 pk = {(__bf16)a0.x, (__bf16)a0.y, (__bf16)a0.z, (__bf16)a0.w,
                     (__bf16)a1.x, (__bf16)a1.y, (__bf16)a1.z, (__bf16)a1.w};
        *(bf16x8*)(k1 + (size_t)e*64 + off + v*8) = pk;
    }
}

// Layer 2 of kernel MLP as MFMA GEMM: [E,64] x [64,128] + b2, relu -> kbf [E,128] bf16.
__global__ __launch_bounds__(256, 2)
void k_edge2(const __bf16* __restrict__ k1, const __bf16* __restrict__ w2sw,
             const float* __restrict__ b2, __bf16* __restrict__ kbf) {
    const int lane = threadIdx.x & 63;
    const int wave = threadIdx.x >> 6;
    const int q = lane >> 4, t = lane & 15;
    const int base = blockIdx.x * 256 + wave * 64;

    bf16x8 af[4][2];
    #pragma unroll
    for (int mt = 0; mt < 4; ++mt) {
        int ea = base + mt*16 + t;
        ea = ea < NE ? ea : NE - 1;
        const __bf16* kr = k1 + (size_t)ea * 64 + q * 8;
        af[mt][0] = *(const bf16x8*)(kr);
        af[mt][1] = *(const bf16x8*)(kr + 32);
    }

    for (int nt = 0; nt < 8; ++nt) {
        f32x4 acc[4];
        #pragma unroll
        for (int mt = 0; mt < 4; ++mt) acc[mt] = (f32x4){0.f, 0.f, 0.f, 0.f};
        #pragma unroll
        for (int ks = 0; ks < 2; ++ks) {
            bf16x8 bf = *(const bf16x8*)(w2sw + ((nt*2 + ks)*64 + lane) * 8);
            #pragma unroll
            for (int mt = 0; mt < 4; ++mt)
                acc[mt] = __builtin_amdgcn_mfma_f32_16x16x32_bf16(af[mt][ks], bf, acc[mt], 0, 0, 0);
        }
        float bias = b2[nt*16 + t];
        #pragma unroll
        for (int mt = 0; mt < 4; ++mt) {
            #pragma unroll
            for (int r = 0; r < 4; ++r) {
                int e = base + mt*16 + q*4 + r;
                if (e < NE)
                    kbf[(size_t)e*128 + nt*16 + t] = (__bf16)fmaxf(acc[mt][r] + bias, 0.f);
            }
        }
    }
}

// Fused big GEMM + einsum epilogue + phi. 4 waves per block, SAME 64 edges;
// each wave owns 8 of the 32 output blocks with a PRIVATE LDS tile -> no
// per-iteration __syncthreads (same-wave LDS ops are in-order). One final
// barrier exchanges mv so wave 0 computes phi. m/phi written with plain
// stores (atomics removed -> CSR gather kernel).
__global__ __launch_bounds__(256, 2)
void k_gemm(const __bf16* __restrict__ kbf, const __bf16* __restrict__ w3sw,
            const float* __restrict__ b3, const float* __restrict__ h,
            const int* __restrict__ eidx,
            const float* __restrict__ cm_w1, const float* __restrict__ cm_b1,
            const float* __restrict__ cm_w2,
            float* __restrict__ m_t, float* __restrict__ phiv) {
    __shared__ float wk[4 * 64 * 36];      // per-wave tile, stride 36
    __shared__ float mvx[32 * 65];         // mv exchange, stride 65 (2-way max)
    const int lane = threadIdx.x & 63;
    const int wave = threadIdx.x >> 6;
    const int q = lane >> 4, t = lane & 15;
    const int base = blockIdx.x * 64;
    float* wkw = wk + wave * (64 * 36);

    int eg = base + lane;
    int egc = eg < NE ? eg : NE - 1;
    int col = eidx[NE + egc];
    float hcol[32];
    const f32x4* hp = (const f32x4*)(h + (size_t)col * 32);
    #pragma unroll
    for (int v = 0; v < 8; ++v) {
        f32x4 hv = hp[v];
        hcol[v*4+0] = hv.x; hcol[v*4+1] = hv.y; hcol[v*4+2] = hv.z; hcol[v*4+3] = hv.w;
    }

    bf16x8 afrag[4][4];
    #pragma unroll
    for (int mt = 0; mt < 4; ++mt) {
        int ea = base + mt*16 + t;
        ea = ea < NE ? ea : NE - 1;
        const __bf16* kr = kbf + (size_t)ea * 128 + q * 8;
        #pragma unroll
        for (int ks = 0; ks < 4; ++ks)
            afrag[mt][ks] = *(const bf16x8*)(kr + ks * 32);
    }

    const float* wkrow = wkw + lane * 36;
    float mv[8];

    for (int ii = 0; ii < 8; ++ii) {
        const int i = wave * 8 + ii;
        f32x4 acc[4][2];
        #pragma unroll
        for (int mt = 0; mt < 4; ++mt) {
            acc[mt][0] = (f32x4){0.f, 0.f, 0.f, 0.f};
            acc[mt][1] = (f32x4){0.f, 0.f, 0.f, 0.f};
        }
        const __bf16* wb = w3sw + (size_t)i * 4096;
        #pragma unroll
        for (int jt = 0; jt < 2; ++jt) {
            #pragma unroll
            for (int ks = 0; ks < 4; ++ks) {
                bf16x8 bfrag = *(const bf16x8*)(wb + ((jt*4 + ks)*64 + lane) * 8);
                #pragma unroll
                for (int mt = 0; mt < 4; ++mt)
                    acc[mt][jt] = __builtin_amdgcn_mfma_f32_16x16x32_bf16(
                        afrag[mt][ks], bfrag, acc[mt][jt], 0, 0, 0);
            }
        }
        float bias0 = b3[i*32 + t];
        float bias1 = b3[i*32 + 16 + t];
        #pragma unroll
        for (int mt = 0; mt < 4; ++mt) {
            #pragma unroll
            for (int r = 0; r < 4; ++r) {
                int row = mt*16 + q*4 + r;
                wkw[row*36 + t]      = acc[mt][0][r] + bias0;
                wkw[row*36 + 16 + t] = acc[mt][1][r] + bias1;
            }
        }
        float s = 0.f;
        #pragma unroll
        for (int v = 0; v < 8; ++v) {
            f32x4 wv = *(const f32x4*)(wkrow + v*4);
            s += wv.x*hcol[v*4+0] + wv.y*hcol[v*4+1] + wv.z*hcol[v*4+2] + wv.w*hcol[v*4+3];
        }
        mv[ii] = s;
    }

    // plain stores of this wave's 8 contiguous m channels
    if (eg < NE) {
        f32x4 v0 = {mv[0], mv[1], mv[2], mv[3]};
        f32x4 v1 = {mv[4], mv[5], mv[6], mv[7]};
        *(f32x4*)(m_t + (size_t)eg*32 + wave*8)     = v0;
        *(f32x4*)(m_t + (size_t)eg*32 + wave*8 + 4) = v1;
    }

    // exchange mv -> wave 0 computes phi
    #pragma unroll
    for (int ii = 0; ii < 8; ++ii)
        mvx[(wave*8 + ii)*65 + lane] = mv[ii];
    __syncthreads();
    if (wave == 0) {
        float m2[32];
        #pragma unroll
        for (int i = 0; i < 32; ++i) m2[i] = mvx[i*65 + lane];
        float phi = 0.f;
        for (int o = 0; o < 32; o += 4) {
            f32x4 a = *(const f32x4*)(cm_b1 + o);
            #pragma unroll
            for (int i = 0; i < 32; ++i)
                a += m2[i] * (*(const f32x4*)(cm_w1 + i*32 + o));
            a = relu4(a);
            f32x4 w2 = *(const f32x4*)(cm_w2 + o);
            phi += a.x*w2.x + a.y*w2.y + a.z*w2.z + a.w*w2.w;
        }
        if (eg < NE) phiv[eg] = phi;
    }
}

// CSR gather: 8 threads per node. Replaces all per-edge atomics.
__global__ __launch_bounds__(256, 4)
void k_gather(const int* __restrict__ rowptr, const int* __restrict__ ebyrow,
              const float* __restrict__ m_t, const float* __restrict__ phiv,
              const float* __restrict__ cd4, const float* __restrict__ deg_inv,
              float* __restrict__ coord, float* __restrict__ h) {
    int tid = blockIdx.x * blockDim.x + threadIdx.x;
    int n = tid >> 3, sub = tid & 7;
    if (n >= NN) return;
    int st = rowptr[n], en = rowptr[n+1];
    f32x4 am = {0.f, 0.f, 0.f, 0.f};
    float cx = 0.f, cy = 0.f, cz = 0.f;
    for (int p = st; p < en; ++p) {
        int e = ebyrow[p];
        am += *(const f32x4*)(m_t + (size_t)e*32 + sub*4);
        if (sub == 0) {
            f32x4 cd = *(const f32x4*)(cd4 + (size_t)e*4);
            float ph = phiv[e];
            cx += cd.x * ph; cy += cd.y * ph; cz += cd.z * ph;
        }
    }
    float di = deg_inv[n];
    f32x4 hv = *(const f32x4*)(h + (size_t)n*32 + sub*4);
    hv = relu4(hv + am * di);
    *(f32x4*)(h + (size_t)n*32 + sub*4) = hv;
    if (sub == 0) {
        coord[n*3+0] += cx * di;
        coord[n*3+1] += cy * di;
        coord[n*3+2] += cz * di;
    }
}

__global__ __launch_bounds__(256, 4)
void k_final(const float* __restrict__ h, const float* __restrict__ coord,
             const float* __restrict__ fw1, const float* __restrict__ fb1,
             const float* __restrict__ fw2, const float* __restrict__ fb2,
             float* __restrict__ out) {
    int n = blockIdx.x * blockDim.x + threadIdx.x;
    if (n >= NN) return;
    float hreg[32];
    #pragma unroll
    for (int i = 0; i < 32; ++i) hreg[i] = h[n*32 + i];
    float ov = fb2[0];
    for (int o = 0; o < 64; o += 4) {
        f32x4 a = *(const f32x4*)(fb1 + o);
        #pragma unroll
        for (int i = 0; i < 32; ++i)
            a += hreg[i] * (*(const f32x4*)(fw1 + i*64 + o));
        a = relu4(a);
        f32x4 w2 = *(const f32x4*)(fw2 + o);
        ov += a.x*w2.x + a.y*w2.y + a.z*w2.z + a.w*w2.w;
    }
    out[n] = ov;                       // output 0: [N,1]
    out[NN + n*3 + 0] = coord[n*3+0];  // output 1: coord [N,3]
    out[NN + n*3 + 1] = coord[n*3+1];
    out[NN + n*3 + 2] = coord[n*3+2];
}

// ---------------- launch ----------------

extern "C" void kernel_launch(void* const* d_in, const int* in_sizes, int n_in,
                              void* d_out, int out_size, void* d_ws, size_t ws_size,
                              hipStream_t stream) {
    const float* x      = (const float*)d_in[0];
    const int*   eidx   = (const int*)  d_in[1];
    const float* eattr  = (const float*)d_in[2];
    const float* cinit  = (const float*)d_in[3];
    const float* fc1w   = (const float*)d_in[4];
    const float* fc1b   = (const float*)d_in[5];
    const float* kw1    = (const float*)d_in[6];
    const float* kb1    = (const float*)d_in[7];
    const float* kw2    = (const float*)d_in[8];
    const float* kb2    = (const float*)d_in[9];
    const float* kw3    = (const float*)d_in[10];
    const float* kb3    = (const float*)d_in[11];
    const float* cmw1   = (const float*)d_in[12];
    const float* cmb1   = (const float*)d_in[13];
    const float* cmw2   = (const float*)d_in[14];
    const float* f2w1   = (const float*)d_in[15];
    const float* f2b1   = (const float*)d_in[16];
    const float* f2w2   = (const float*)d_in[17];
    const float* f2b2   = (const float*)d_in[18];
    float* out = (float*)d_out;

    // workspace carve-up (256B aligned slots)
    char* p = (char*)d_ws;
    auto carve = [&](size_t bytes) {
        void* r = (void*)p;
        p += (bytes + 255) & ~(size_t)255;
        return r;
    };
    float*  h        = (float*) carve((size_t)NN * 32 * 4);
    float*  coord    = (float*) carve((size_t)NN * 3 * 4);
    int*    deg      = (int*)   carve((size_t)NN * 4);
    float*  deg_inv  = (float*) carve((size_t)NN * 4);
    int*    rowptr   = (int*)   carve((size_t)(NN + 1) * 4);
    int*    cursor   = (int*)   carve((size_t)NN * 4);
    int*    ebyrow   = (int*)   carve((size_t)NE * 4);
    float*  cd4      = (float*) carve((size_t)NE * 4 * 4);
    float*  m_t      = (float*) carve((size_t)NE * 32 * 4);
    float*  phiv     = (float*) carve((size_t)NE * 4);
    __bf16* k1       = (__bf16*)carve((size_t)NE * 64 * 2);
    __bf16* kbf      = (__bf16*)carve((size_t)NE * 128 * 2);
    __bf16* w3sw     = (__bf16*)carve((size_t)131072 * 2);
    __bf16* w2sw     = (__bf16*)carve((size_t)8192 * 2);

    const int TB = 256;
    dim3 gE((NE + TB - 1) / TB), gN((NN + TB - 1) / TB), b(TB);
    dim3 gE2((2*NE + TB - 1) / TB);          // 2 threads per edge
    dim3 gW((NE + 255) / 256);               // 4 waves x 64 edges (k_edge2)
    dim3 gG((NE + 63) / 64);                 // 64 edges per block (k_gemm, 256 thr)
    dim3 gA((NN*8 + TB - 1) / TB);           // 8 threads per node (k_gather)

    hipMemsetAsync(deg, 0, (size_t)NN * 4, stream);
    k_deg <<<gE, b, 0, stream>>>(eidx, deg);
    k_scan<<<1, b, 0, stream>>>(deg, rowptr, cursor);
    k_fill<<<gE, b, 0, stream>>>(eidx, cursor, ebyrow);
    k_init<<<gN, b, 0, stream>>>(x, fc1w, fc1b, cinit, deg, h, coord, deg_inv);
    k_w3sw<<<512, b, 0, stream>>>(kw3, w3sw);
    k_w2sw<<<32, b, 0, stream>>>(kw2, w2sw);

    for (int d = 0; d < 3; ++d) {
        k_edge1<<<gE2, b, 0, stream>>>(coord, eidx, eattr, kw1, kb1, cd4, k1);
        k_edge2<<<gW, b, 0, stream>>>(k1, w2sw, kb2, kbf);
        k_gemm <<<gG, b, 0, stream>>>(
            kbf, w3sw, kb3, h, eidx, cmw1, cmb1, cmw2, m_t, phiv);
        k_gather<<<gA, b, 0, stream>>>(rowptr, ebyrow, m_t, phiv, cd4, deg_inv, coord, h);
    }
    k_final<<<gN, b, 0, stream>>>(h, coord, f2w1, f2b1, f2w2, f2b2, out);
}

// Round 7
// 470.146 us; speedup vs baseline: 7.5455x; 1.2234x over previous
//
#include <hip/hip_runtime.h>
#include <hip/hip_bf16.h>

#define NN 10000
#define NE 100000

typedef __bf16 bf16x8 __attribute__((ext_vector_type(8)));
typedef __bf16 bf16x4 __attribute__((ext_vector_type(4)));
typedef float  f32x4  __attribute__((ext_vector_type(4)));

__device__ __forceinline__ f32x4 relu4(f32x4 a) {
    a.x = fmaxf(a.x, 0.f); a.y = fmaxf(a.y, 0.f);
    a.z = fmaxf(a.z, 0.f); a.w = fmaxf(a.w, 0.f);
    return a;
}

// ---------------- one-time kernels ----------------

__global__ void k_deg(const int* __restrict__ eidx, int* __restrict__ deg) {
    int e = blockIdx.x * blockDim.x + threadIdx.x;
    if (e < NE) atomicAdd(&deg[eidx[e]], 1);
}

// Single-block exclusive scan over deg -> rowptr[NN+1], cursor copy.
__global__ void k_scan(const int* __restrict__ deg, int* __restrict__ rowptr,
                       int* __restrict__ cursor) {
    __shared__ int ssum[256];
    const int tid = threadIdx.x;
    const int CH = 40;                       // 256*40 >= 10000
    const int base = tid * CH;
    int s = 0;
    for (int i = 0; i < CH; ++i) { int n = base + i; if (n < NN) s += deg[n]; }
    ssum[tid] = s;
    __syncthreads();
    for (int off = 1; off < 256; off <<= 1) {
        int t = (tid >= off) ? ssum[tid - off] : 0;
        __syncthreads();
        ssum[tid] += t;
        __syncthreads();
    }
    int run = ssum[tid] - s;                 // exclusive prefix
    for (int i = 0; i < CH; ++i) {
        int n = base + i;
        if (n < NN) { rowptr[n] = run; cursor[n] = run; run += deg[n]; }
    }
    if (tid == 255) rowptr[NN] = ssum[255];
}

__global__ void k_fill(const int* __restrict__ eidx, int* __restrict__ cursor,
                       int* __restrict__ ebyrow) {
    int e = blockIdx.x * blockDim.x + threadIdx.x;
    if (e < NE) {
        int r = eidx[e];
        int slot = atomicAdd(&cursor[r], 1);
        ebyrow[slot] = e;
    }
}

__global__ void k_init(const float* __restrict__ x, const float* __restrict__ fc1w,
                       const float* __restrict__ fc1b, const float* __restrict__ cinit,
                       const int* __restrict__ deg,
                       float* __restrict__ h, float* __restrict__ coord,
                       float* __restrict__ deg_inv) {
    int n = blockIdx.x * blockDim.x + threadIdx.x;
    if (n >= NN) return;
    float x0 = x[n*3+0], x1 = x[n*3+1], x2 = x[n*3+2];
    #pragma unroll
    for (int j = 0; j < 32; j += 4) {
        f32x4 a = *(const f32x4*)(fc1b + j);
        a += x0 * (*(const f32x4*)(fc1w + 0*32 + j));
        a += x1 * (*(const f32x4*)(fc1w + 1*32 + j));
        a += x2 * (*(const f32x4*)(fc1w + 2*32 + j));
        *(f32x4*)(h + n*32 + j) = a;   // no relu on fc1 (matches reference)
    }
    coord[n*3+0] = cinit[n*3+0];
    coord[n*3+1] = cinit[n*3+1];
    coord[n*3+2] = cinit[n*3+2];
    int d = deg[n];
    deg_inv[n] = 1.0f / (float)(d > 1 ? d : 1);
}

// Swizzle ker_w3 [128,1024] and ker_w2 [64,128] fp32 -> bf16 MFMA-B fragment order.
__global__ void k_wsw(const float* __restrict__ w3, __bf16* __restrict__ w3sw,
                      const float* __restrict__ w2, __bf16* __restrict__ w2sw) {
    int t = blockIdx.x * blockDim.x + threadIdx.x;
    if (t < 131072) {
        int jj = t & 7;
        int L  = (t >> 3) & 63;
        int ks = (t >> 9) & 3;
        int jt = (t >> 11) & 1;
        int i  = t >> 12;
        int c    = ks*32 + (L >> 4)*8 + jj;              // K index 0..127
        int colv = i*32 + jt*16 + (L & 15);              // output col 0..1023
        w3sw[t] = (__bf16)w3[c*1024 + colv];
    } else if (t < 131072 + 8192) {
        int u = t - 131072;
        int jj = u & 7;
        int L  = (u >> 3) & 63;
        int ks = (u >> 9) & 1;
        int nt = u >> 10;                                // 0..7
        int c1 = ks*32 + (L >> 4)*8 + jj;                // K index 0..63
        int c2 = nt*16 + (L & 15);                       // output col 0..127
        w2sw[u] = (__bf16)w2[c1*128 + c2];
    }
}

// ---------------- per-layer kernels ----------------

// Fused edge MLP: coord_diff/radial -> layer1 (per-lane, 64ch in regs) ->
// XOR-swizzled per-wave LDS tile -> A-frags -> layer2 MFMA -> kbf [E,128] bf16.
// 4 waves/block, 64 edges per wave, 256 edges per block.
__global__ __launch_bounds__(256, 2)
void k_edge12(const float* __restrict__ coord, const int* __restrict__ eidx,
              const float* __restrict__ eattr,
              const float* __restrict__ w1, const float* __restrict__ b1,
              const __bf16* __restrict__ w2sw, const float* __restrict__ b2,
              float* __restrict__ cd4, __bf16* __restrict__ kbf) {
    __shared__ __bf16 ktile[4][4096];       // per-wave 64x64 bf16 tile, XOR-swizzled
    const int tid = threadIdx.x;
    const int wave = tid >> 6, lane = tid & 63;
    const int q = lane >> 4, t = lane & 15;
    const int e = blockIdx.x * 256 + tid;
    const int ec = e < NE ? e : NE - 1;
    const int wbase = blockIdx.x * 256 + wave * 64;
    __bf16* kt = ktile[wave];

    // ---- layer 1: this lane's edge, all 64 channels in registers ----
    int r = eidx[ec], c = eidx[NE + ec];
    float dx = coord[r*3+0] - coord[c*3+0];
    float dy = coord[r*3+1] - coord[c*3+1];
    float dz = coord[r*3+2] - coord[c*3+2];
    float rad = dx*dx + dy*dy + dz*dz;
    if (e < NE) {
        f32x4 cdv = {dx, dy, dz, rad};
        *(f32x4*)(cd4 + (size_t)e*4) = cdv;
    }
    float kin[7];
    #pragma unroll
    for (int a = 0; a < 6; ++a) kin[a] = eattr[(size_t)ec*6 + a];
    kin[6] = rad;

    f32x4 acc1[16];
    #pragma unroll
    for (int g = 0; g < 16; ++g) acc1[g] = *(const f32x4*)(b1 + g*4);
    #pragma unroll
    for (int t7 = 0; t7 < 7; ++t7) {
        float kv = kin[t7];
        #pragma unroll
        for (int g = 0; g < 16; ++g)
            acc1[g] += kv * (*(const f32x4*)(w1 + t7*64 + g*4));
    }
    // relu -> bf16 -> swizzled LDS write (8 chunks of 8 bf16)
    #pragma unroll
    for (int cc = 0; cc < 8; ++cc) {
        f32x4 a0 = relu4(acc1[cc*2]), a1 = relu4(acc1[cc*2+1]);
        bf16x8 pk = {(__bf16)a0.x, (__bf16)a0.y, (__bf16)a0.z, (__bf16)a0.w,
                     (__bf16)a1.x, (__bf16)a1.y, (__bf16)a1.z, (__bf16)a1.w};
        *(bf16x8*)(kt + lane*64 + ((cc ^ (lane & 7)) * 8)) = pk;
    }
    __syncthreads();   // cheap insurance for LDS write->cross-lane-read ordering

    // ---- read A-frags from the swizzled tile ----
    bf16x8 af[4][2];
    #pragma unroll
    for (int mt = 0; mt < 4; ++mt) {
        int ep = mt*16 + t;
        #pragma unroll
        for (int ks = 0; ks < 2; ++ks)
            af[mt][ks] = *(const bf16x8*)(kt + ep*64 + (((ks*4 + q) ^ (ep & 7)) * 8));
    }

    // ---- layer 2 MFMA: [64e x 64k] x [64k x 128] ----
    for (int nt = 0; nt < 8; ++nt) {
        f32x4 a2[4];
        #pragma unroll
        for (int mt = 0; mt < 4; ++mt) a2[mt] = (f32x4){0.f, 0.f, 0.f, 0.f};
        #pragma unroll
        for (int ks = 0; ks < 2; ++ks) {
            bf16x8 bf_ = *(const bf16x8*)(w2sw + ((nt*2 + ks)*64 + lane) * 8);
            #pragma unroll
            for (int mt = 0; mt < 4; ++mt)
                a2[mt] = __builtin_amdgcn_mfma_f32_16x16x32_bf16(af[mt][ks], bf_, a2[mt], 0, 0, 0);
        }
        float bias = b2[nt*16 + t];
        #pragma unroll
        for (int mt = 0; mt < 4; ++mt) {
            #pragma unroll
            for (int rr = 0; rr < 4; ++rr) {
                int e2 = wbase + mt*16 + q*4 + rr;
                if (e2 < NE)
                    kbf[(size_t)e2*128 + nt*16 + t] = (__bf16)fmaxf(a2[mt][rr] + bias, 0.f);
            }
        }
    }
}

// Fused big GEMM + einsum epilogue + phi. 4 waves per block, SAME 64 edges;
// each wave owns 8 of the 32 output blocks with a PRIVATE LDS tile (no
// per-iteration barrier). B-fragments for i+1 are prefetched into registers
// during the LDS-exchange/dot phase of i (hides ~200cyc L2 latency).
// mvx exchange LDS is unioned into the wk region (36.9 KB total).
__global__ __launch_bounds__(256, 2)
void k_gemm(const __bf16* __restrict__ kbf, const __bf16* __restrict__ w3sw,
            const float* __restrict__ b3, const float* __restrict__ h,
            const int* __restrict__ eidx,
            const float* __restrict__ cm_w1, const float* __restrict__ cm_b1,
            const float* __restrict__ cm_w2,
            float* __restrict__ m_t, float* __restrict__ phiv) {
    __shared__ float smem[4 * 64 * 36];    // per-wave wk tiles; reused for mv exchange
    const int lane = threadIdx.x & 63;
    const int wave = threadIdx.x >> 6;
    const int q = lane >> 4, t = lane & 15;
    const int base = blockIdx.x * 64;
    float* wkw = smem + wave * (64 * 36);

    int eg = base + lane;
    int egc = eg < NE ? eg : NE - 1;
    int col = eidx[NE + egc];
    float hcol[32];
    const f32x4* hp = (const f32x4*)(h + (size_t)col * 32);
    #pragma unroll
    for (int v = 0; v < 8; ++v) {
        f32x4 hv = hp[v];
        hcol[v*4+0] = hv.x; hcol[v*4+1] = hv.y; hcol[v*4+2] = hv.z; hcol[v*4+3] = hv.w;
    }

    bf16x8 afrag[4][4];
    #pragma unroll
    for (int mt = 0; mt < 4; ++mt) {
        int ea = base + mt*16 + t;
        ea = ea < NE ? ea : NE - 1;
        const __bf16* kr = kbf + (size_t)ea * 128 + q * 8;
        #pragma unroll
        for (int ks = 0; ks < 4; ++ks)
            afrag[mt][ks] = *(const bf16x8*)(kr + ks * 32);
    }

    const float* wkrow = wkw + lane * 36;
    float mv[8];

    // preload B-fragments for first i
    bf16x8 bcur[8];
    {
        const __bf16* wb0 = w3sw + (size_t)(wave * 8) * 4096;
        #pragma unroll
        for (int f = 0; f < 8; ++f)
            bcur[f] = *(const bf16x8*)(wb0 + (f*64 + lane) * 8);
    }

    #pragma unroll
    for (int ii = 0; ii < 8; ++ii) {
        const int i = wave * 8 + ii;
        f32x4 acc[4][2];
        #pragma unroll
        for (int mt = 0; mt < 4; ++mt) {
            acc[mt][0] = (f32x4){0.f, 0.f, 0.f, 0.f};
            acc[mt][1] = (f32x4){0.f, 0.f, 0.f, 0.f};
        }
        #pragma unroll
        for (int jt = 0; jt < 2; ++jt) {
            #pragma unroll
            for (int ks = 0; ks < 4; ++ks) {
                bf16x8 bfrag = bcur[jt*4 + ks];
                #pragma unroll
                for (int mt = 0; mt < 4; ++mt)
                    acc[mt][jt] = __builtin_amdgcn_mfma_f32_16x16x32_bf16(
                        afrag[mt][ks], bfrag, acc[mt][jt], 0, 0, 0);
            }
        }
        // prefetch next i's B-fragments while we do the LDS exchange + dot
        if (ii < 7) {
            const __bf16* wbn = w3sw + (size_t)(i + 1) * 4096;
            #pragma unroll
            for (int f = 0; f < 8; ++f)
                bcur[f] = *(const bf16x8*)(wbn + (f*64 + lane) * 8);
        }
        float bias0 = b3[i*32 + t];
        float bias1 = b3[i*32 + 16 + t];
        #pragma unroll
        for (int mt = 0; mt < 4; ++mt) {
            #pragma unroll
            for (int r = 0; r < 4; ++r) {
                int row = mt*16 + q*4 + r;
                wkw[row*36 + t]      = acc[mt][0][r] + bias0;
                wkw[row*36 + 16 + t] = acc[mt][1][r] + bias1;
            }
        }
        float s = 0.f;
        #pragma unroll
        for (int v = 0; v < 8; ++v) {
            f32x4 wv = *(const f32x4*)(wkrow + v*4);
            s += wv.x*hcol[v*4+0] + wv.y*hcol[v*4+1] + wv.z*hcol[v*4+2] + wv.w*hcol[v*4+3];
        }
        mv[ii] = s;
    }

    // plain stores of this wave's 8 contiguous m channels
    if (eg < NE) {
        f32x4 v0 = {mv[0], mv[1], mv[2], mv[3]};
        f32x4 v1 = {mv[4], mv[5], mv[6], mv[7]};
        *(f32x4*)(m_t + (size_t)eg*32 + wave*8)     = v0;
        *(f32x4*)(m_t + (size_t)eg*32 + wave*8 + 4) = v1;
    }

    // exchange mv (reusing smem) -> wave 0 computes phi
    __syncthreads();                       // wk no longer needed by any wave
    float* mvx = smem;                     // 32*65 floats, stride 65
    #pragma unroll
    for (int ii = 0; ii < 8; ++ii)
        mvx[(wave*8 + ii)*65 + lane] = mv[ii];
    __syncthreads();
    if (wave == 0) {
        float m2[32];
        #pragma unroll
        for (int i = 0; i < 32; ++i) m2[i] = mvx[i*65 + lane];
        float phi = 0.f;
        for (int o = 0; o < 32; o += 4) {
            f32x4 a = *(const f32x4*)(cm_b1 + o);
            #pragma unroll
            for (int i = 0; i < 32; ++i)
                a += m2[i] * (*(const f32x4*)(cm_w1 + i*32 + o));
            a = relu4(a);
            f32x4 w2 = *(const f32x4*)(cm_w2 + o);
            phi += a.x*w2.x + a.y*w2.y + a.z*w2.z + a.w*w2.w;
        }
        if (eg < NE) phiv[eg] = phi;
    }
}

// CSR gather: 8 threads per node. Replaces all per-edge atomics.
__global__ __launch_bounds__(256, 4)
void k_gather(const int* __restrict__ rowptr, const int* __restrict__ ebyrow,
              const float* __restrict__ m_t, const float* __restrict__ phiv,
              const float* __restrict__ cd4, const float* __restrict__ deg_inv,
              float* __restrict__ coord, float* __restrict__ h) {
    int tid = blockIdx.x * blockDim.x + threadIdx.x;
    int n = tid >> 3, sub = tid & 7;
    if (n >= NN) return;
    int st = rowptr[n], en = rowptr[n+1];
    f32x4 am = {0.f, 0.f, 0.f, 0.f};
    float cx = 0.f, cy = 0.f, cz = 0.f;
    for (int p = st; p < en; ++p) {
        int e = ebyrow[p];
        am += *(const f32x4*)(m_t + (size_t)e*32 + sub*4);
        if (sub == 0) {
            f32x4 cd = *(const f32x4*)(cd4 + (size_t)e*4);
            float ph = phiv[e];
            cx += cd.x * ph; cy += cd.y * ph; cz += cd.z * ph;
        }
    }
    float di = deg_inv[n];
    f32x4 hv = *(const f32x4*)(h + (size_t)n*32 + sub*4);
    hv = relu4(hv + am * di);
    *(f32x4*)(h + (size_t)n*32 + sub*4) = hv;
    if (sub == 0) {
        coord[n*3+0] += cx * di;
        coord[n*3+1] += cy * di;
        coord[n*3+2] += cz * di;
    }
}

__global__ __launch_bounds__(256, 4)
void k_final(const float* __restrict__ h, const float* __restrict__ coord,
             const float* __restrict__ fw1, const float* __restrict__ fb1,
             const float* __restrict__ fw2, const float* __restrict__ fb2,
             float* __restrict__ out) {
    int n = blockIdx.x * blockDim.x + threadIdx.x;
    if (n >= NN) return;
    float hreg[32];
    #pragma unroll
    for (int i = 0; i < 32; ++i) hreg[i] = h[n*32 + i];
    float ov = fb2[0];
    for (int o = 0; o < 64; o += 4) {
        f32x4 a = *(const f32x4*)(fb1 + o);
        #pragma unroll
        for (int i = 0; i < 32; ++i)
            a += hreg[i] * (*(const f32x4*)(fw1 + i*64 + o));
        a = relu4(a);
        f32x4 w2 = *(const f32x4*)(fw2 + o);
        ov += a.x*w2.x + a.y*w2.y + a.z*w2.z + a.w*w2.w;
    }
    out[n] = ov;                       // output 0: [N,1]
    out[NN + n*3 + 0] = coord[n*3+0];  // output 1: coord [N,3]
    out[NN + n*3 + 1] = coord[n*3+1];
    out[NN + n*3 + 2] = coord[n*3+2];
}

// ---------------- launch ----------------

extern "C" void kernel_launch(void* const* d_in, const int* in_sizes, int n_in,
                              void* d_out, int out_size, void* d_ws, size_t ws_size,
                              hipStream_t stream) {
    const float* x      = (const float*)d_in[0];
    const int*   eidx   = (const int*)  d_in[1];
    const float* eattr  = (const float*)d_in[2];
    const float* cinit  = (const float*)d_in[3];
    const float* fc1w   = (const float*)d_in[4];
    const float* fc1b   = (const float*)d_in[5];
    const float* kw1    = (const float*)d_in[6];
    const float* kb1    = (const float*)d_in[7];
    const float* kw2    = (const float*)d_in[8];
    const float* kb2    = (const float*)d_in[9];
    const float* kw3    = (const float*)d_in[10];
    const float* kb3    = (const float*)d_in[11];
    const float* cmw1   = (const float*)d_in[12];
    const float* cmb1   = (const float*)d_in[13];
    const float* cmw2   = (const float*)d_in[14];
    const float* f2w1   = (const float*)d_in[15];
    const float* f2b1   = (const float*)d_in[16];
    const float* f2w2   = (const float*)d_in[17];
    const float* f2b2   = (const float*)d_in[18];
    float* out = (float*)d_out;

    // workspace carve-up (256B aligned slots)
    char* p = (char*)d_ws;
    auto carve = [&](size_t bytes) {
        void* r = (void*)p;
        p += (bytes + 255) & ~(size_t)255;
        return r;
    };
    float*  h        = (float*) carve((size_t)NN * 32 * 4);
    float*  coord    = (float*) carve((size_t)NN * 3 * 4);
    int*    deg      = (int*)   carve((size_t)NN * 4);
    float*  deg_inv  = (float*) carve((size_t)NN * 4);
    int*    rowptr   = (int*)   carve((size_t)(NN + 1) * 4);
    int*    cursor   = (int*)   carve((size_t)NN * 4);
    int*    ebyrow   = (int*)   carve((size_t)NE * 4);
    float*  cd4      = (float*) carve((size_t)NE * 4 * 4);
    float*  m_t      = (float*) carve((size_t)NE * 32 * 4);
    float*  phiv     = (float*) carve((size_t)NE * 4);
    __bf16* kbf      = (__bf16*)carve((size_t)NE * 128 * 2);
    __bf16* w3sw     = (__bf16*)carve((size_t)131072 * 2);
    __bf16* w2sw     = (__bf16*)carve((size_t)8192 * 2);

    const int TB = 256;
    dim3 gE((NE + TB - 1) / TB), gN((NN + TB - 1) / TB), b(TB);
    dim3 gF((NE + 255) / 256);               // 4 waves x 64 edges (k_edge12)
    dim3 gG((NE + 63) / 64);                 // 64 edges per block (k_gemm, 256 thr)
    dim3 gA((NN*8 + TB - 1) / TB);           // 8 threads per node (k_gather)

    hipMemsetAsync(deg, 0, (size_t)NN * 4, stream);
    k_deg <<<gE, b, 0, stream>>>(eidx, deg);
    k_scan<<<1, b, 0, stream>>>(deg, rowptr, cursor);
    k_fill<<<gE, b, 0, stream>>>(eidx, cursor, ebyrow);
    k_init<<<gN, b, 0, stream>>>(x, fc1w, fc1b, cinit, deg, h, coord, deg_inv);
    k_wsw <<<544, b, 0, stream>>>(kw3, w3sw, kw2, w2sw);

    for (int d = 0; d < 3; ++d) {
        k_edge12<<<gF, b, 0, stream>>>(coord, eidx, eattr, kw1, kb1, w2sw, kb2, cd4, kbf);
        k_gemm  <<<gG, b, 0, stream>>>(
            kbf, w3sw, kb3, h, eidx, cmw1, cmb1, cmw2, m_t, phiv);
        k_gather<<<gA, b, 0, stream>>>(rowptr, ebyrow, m_t, phiv, cd4, deg_inv, coord, h);
    }
    k_final<<<gN, b, 0, stream>>>(h, coord, f2w1, f2b1, f2w2, f2b2, out);
}